// Round 18
// baseline (776.197 us; speedup 1.0000x reference)
//
#include <hip/hip_runtime.h>

typedef __attribute__((ext_vector_type(8))) short bf16x8;
typedef __attribute__((ext_vector_type(4))) float f32x4;
typedef __attribute__((ext_vector_type(8))) unsigned short u16x8;

__device__ __forceinline__ unsigned short f2bf(float f) {
  union { float f; unsigned u; } v; v.f = f;
  unsigned r = v.u + 0x7fffu + ((v.u >> 16) & 1u);
  return (unsigned short)(r >> 16);
}

// ================= merged prep: cvt_x | trA | trB | compact | row-stats =================
// grid: [0,2048) cvt_x | [2048,4096) trA | [4096,6144) trB | [6144,6160) compact | [6160,6176) stats
__global__ __launch_bounds__(256)
void prep_kernel(const float* __restrict__ x, unsigned short* __restrict__ x_bf,
                 const float* __restrict__ A, unsigned short* __restrict__ A_t,
                 const float* __restrict__ B, unsigned short* __restrict__ B_t,
                 const int* __restrict__ mask, int* __restrict__ rows,
                 int* __restrict__ counts, unsigned* __restrict__ kmask,
                 int* __restrict__ done, int* __restrict__ target,
                 const float* __restrict__ bias, float* __restrict__ out) {
  __shared__ float tbuf[64][65];
  __shared__ int cnt, mcnt;
  const int bid = blockIdx.x;
  const int t = threadIdx.x;

  if (bid < 2048) {  // ---- cvt_x ----
    int slot = bid * 256 + t;
    f32x4 v0 = __builtin_nontemporal_load((const f32x4*)x + 2 * slot);
    f32x4 v1 = __builtin_nontemporal_load((const f32x4*)x + 2 * slot + 1);
    u16x8 o;
    o[0] = f2bf(v0[0]); o[1] = f2bf(v0[1]); o[2] = f2bf(v0[2]); o[3] = f2bf(v0[3]);
    o[4] = f2bf(v1[0]); o[5] = f2bf(v1[1]); o[6] = f2bf(v1[2]); o[7] = f2bf(v1[3]);
    ((u16x8*)x_bf)[slot] = o;
    return;
  }
  if (bid < 6144) {  // ---- transpose+convert, 64x64 tiles ----
    const float* in; unsigned short* out_p; int R, C, cx, ry, z;
    if (bid < 4096) {  // A: [16][1024][512] -> [16][512][1024]
      int idx = bid - 2048; z = idx >> 7; int local = idx & 127;
      R = 1024; C = 512; cx = local & 7; ry = local >> 3;
      in = A; out_p = A_t;
    } else {           // B: [16][512][1024] -> [16][1024][512]
      int idx = bid - 4096; z = idx >> 7; int local = idx & 127;
      R = 512; C = 1024; cx = local & 15; ry = local >> 4;
      in = B; out_p = B_t;
    }
    size_t eo = (size_t)z * R * C;
    const float* src = in + eo;
    unsigned short* dst = out_p + eo;
    int c0 = cx * 64, r0 = ry * 64;
    int tx = t & 63, ty = t >> 6;  // (64,4)
#pragma unroll
    for (int i = 0; i < 64; i += 4)
      tbuf[ty + i][tx] = __builtin_nontemporal_load(&src[(size_t)(r0 + ty + i) * C + (c0 + tx)]);
    __syncthreads();
#pragma unroll
    for (int i = 0; i < 64; i += 4)
      dst[(size_t)(c0 + ty + i) * R + (r0 + tx)] = f2bf(tbuf[tx][ty + i]);
    return;
  }
  if (bid < 6160) {  // ---- compact (complement tail) ----
    int z = bid - 6144;
    if (t == 0) { cnt = 0; mcnt = 0; }
    __syncthreads();
    int* rz = rows + (size_t)z * 4096;
    for (int i = t; i < 4096; i += 256) {
      bool m = mask[(size_t)i * 16 + z] != 0;
      unsigned long long bal = __ballot(m);
      int lane = t & 63;
      int pa = __popcll(bal & ((1ull << lane) - 1ull));
      int ta = __popcll(bal);
      int base_a, base_m;
      if (lane == 0) { base_a = atomicAdd(&cnt, ta); base_m = atomicAdd(&mcnt, 64 - ta); }
      base_a = __shfl(base_a, 0);
      base_m = __shfl(base_m, 0);
      int pm = lane - pa;
      if (m) rz[base_a + pa] = i;
      else   rz[4095 - (base_m + pm)] = i;
    }
    __syncthreads();
    if (t == 0) counts[z] = cnt;
    return;
  }
  // ---- row-stats: kmask[b], target[b]=8*nact, done[b]=0; out=bias for nact==0 ----
  {
    int b = (bid - 6160) * 256 + t;
    const int* mp = mask + (size_t)b * 16;
    unsigned km = 0;
#pragma unroll
    for (int k = 0; k < 16; ++k)
      if (mp[k]) km |= (1u << k);
    kmask[b] = km;
    int nact = __popc(km);
    target[b] = 8 * nact;
    done[b] = 0;
    if (nact == 0) {  // no expert contributes: out = bias (rare: P ~ 2^-16 per row)
      for (int h = 0; h < 1024; ++h) out[(size_t)b * 1024 + h] = bias[h];
    }
  }
}

// ================= GEMM building blocks (r11 structure) =================
__device__ __forceinline__ void stage_tile(const unsigned short* __restrict__ src,
                                           size_t row_stride, int row0, int k0,
                                           unsigned short* lds) {
  int t = threadIdx.x;
  int lane = t & 63;
  int w = t >> 6;
#pragma unroll
  for (int i = 0; i < 4; ++i) {
    int chunk = w * 4 + i;
    int row = chunk * 8 + (lane >> 3);
    int glog = (lane & 7) ^ (row & 7);
    const unsigned short* g = src + (size_t)(row0 + row) * row_stride + (size_t)(k0 + glog * 8);
    __builtin_amdgcn_global_load_lds((const __attribute__((address_space(1))) unsigned int*)g,
                                     (__attribute__((address_space(3))) unsigned int*)(lds + chunk * 512),
                                     16, 0, 0);
  }
}

__device__ __forceinline__ bf16x8 read_frag(const unsigned short* lds, int row, int gb) {
  int phys = (row * 128 + gb) ^ ((row & 7) << 4);
  return *(const bf16x8*)((const char*)lds + phys);
}

// ================= GEMM1 + fused masked-inner zero-fill (r17) =================
__global__ __launch_bounds__(256)
void gemm1_kernel(const unsigned short* __restrict__ X,
                  const unsigned short* __restrict__ W,
                  unsigned short* __restrict__ pre_out,
                  float* __restrict__ inner_out,
                  const int* __restrict__ rows,
                  const int* __restrict__ counts) {
  const int o = blockIdx.x;
  const int chunk = o & 7;
  const int pos = o >> 3;
  const int t = threadIdx.x;

  if (pos >= 256) {  // ---- zero-fill block: masked rows of this chunk's experts ----
    int w = chunk * 256 + (pos - 256);
    int z = w >> 7;
    int sub = w & 127;
    int cnt = counts[z];
    int slot0 = cnt + sub * 32;
    if (slot0 >= 4096) return;
    const int* rz = rows + (size_t)z * 4096;
    const f32x4 z4 = {0.f, 0.f, 0.f, 0.f};
#pragma unroll 4
    for (int i = 0; i < 32; ++i) {
      int slot = slot0 + i;
      if (slot >= 4096) break;
      int b = rz[slot];
      f32x4* p = (f32x4*)(inner_out + (size_t)b * (16 * 1024) + (size_t)z * 1024) + t;
      __builtin_nontemporal_store(z4, p);
    }
    return;
  }

  int g = chunk * 256 + pos;
  const int bx = g & 3;
  const int by = (g >> 2) & 31;
  const int z = g >> 7;
  const int cnt = counts[z];
  const int tb = by * 128;
  const int tn = bx * 128;
  if (tb >= cnt) return;

  __shared__ unsigned short Xs[128 * 64];
  __shared__ unsigned short Ws[128 * 64];
  __shared__ int rowsS[128];

  if (t < 128) rowsS[t] = rows[(size_t)z * 4096 + tb + t];
  __syncthreads();

  const int lane = t & 63;
  const int wv = t >> 6;
  const int wr = (wv >> 1) * 64;
  const int wc = (wv & 1) * 64;
  const int fr = lane & 15;
  const int fg = lane >> 4;

  const unsigned short* Wbase = W + (size_t)z * 512 * 1024;

  int xoff[4];
#pragma unroll
  for (int i = 0; i < 4; ++i) {
    int chnk = wv * 4 + i;
    int row = chnk * 8 + (lane >> 3);
    int glog = (lane & 7) ^ (row & 7);
    xoff[i] = rowsS[row] * 1024 + glog * 8;
  }

  f32x4 acc[4][4] = {};

  for (int kt = 0; kt < 16; ++kt) {
    if (kt) __syncthreads();
    {
      const int k64 = kt * 64;
#pragma unroll
      for (int i = 0; i < 4; ++i) {
        int chnk = wv * 4 + i;
        __builtin_amdgcn_global_load_lds(
            (const __attribute__((address_space(1))) unsigned int*)(X + xoff[i] + k64),
            (__attribute__((address_space(3))) unsigned int*)(Xs + chnk * 512), 16, 0, 0);
      }
    }
    stage_tile(Wbase, 1024, tn, kt * 64, Ws);
    __syncthreads();
#pragma unroll
    for (int kk = 0; kk < 2; ++kk) {
      const int gb = kk * 64 + fg * 16;
      bf16x8 xf[4], wf[4];
#pragma unroll
      for (int i = 0; i < 4; ++i) {
        xf[i] = read_frag(Xs, wr + i * 16 + fr, gb);
        wf[i] = read_frag(Ws, wc + i * 16 + fr, gb);
      }
#pragma unroll
      for (int mi = 0; mi < 4; ++mi)
#pragma unroll
        for (int ni = 0; ni < 4; ++ni)
          acc[mi][ni] = __builtin_amdgcn_mfma_f32_16x16x32_bf16(xf[mi], wf[ni], acc[mi][ni], 0, 0, 0);
    }
  }

#pragma unroll
  for (int mi = 0; mi < 4; ++mi) {
#pragma unroll
    for (int j = 0; j < 4; ++j) {
      int rl = wr + mi * 16 + fg * 4 + j;
      size_t rowbase = (size_t)z * 4096 * 512 + (size_t)(tb + rl) * 512;
#pragma unroll
      for (int ni = 0; ni < 4; ++ni) {
        int m = tn + wc + ni * 16 + fr;
        pre_out[rowbase + m] = f2bf(acc[mi][ni][j]);
      }
    }
  }
}

// ================= GEMM2 + fused last-writer reduce =================
// After storing its inner tile: release (threadfence -> wbl2, syncthreads), then per-row
// atomicAdd(done[b]). The unique thread seeing target-1 queues b; block cooperatively
// computes out[b] = bias + sum_{k in kmask} inner[b][k] (nt loads; own-XCD lines fresh,
// remote lines fresh-from-LLC after writers' release fences).
__global__ __launch_bounds__(256)
void gemm2_kernel(const unsigned short* __restrict__ X,
                  const unsigned short* __restrict__ W,
                  float* __restrict__ inner_out,
                  const int* __restrict__ rows,
                  const int* __restrict__ counts,
                  int* __restrict__ done,
                  const int* __restrict__ target,
                  const unsigned* __restrict__ kmask,
                  const float* __restrict__ bias,
                  float* __restrict__ out) {
  const int gx = gridDim.x, gy = gridDim.y;
  int lin = blockIdx.x + gx * (blockIdx.y + gy * blockIdx.z);
  int cpx = (gx * gy * gridDim.z) >> 3;
  lin = (lin & 7) * cpx + (lin >> 3);
  int bx = lin % gx; lin /= gx;
  int by = lin % gy; lin /= gy;
  const int z = lin;
  const int cnt = counts[z];
  const int tb = by * 128;
  const int tn = bx * 128;
  const int t = threadIdx.x;

  if (tb >= cnt) return;  // masked rows zero-filled in gemm1 dispatch

  __shared__ unsigned short Xs[128 * 64];
  __shared__ unsigned short Ws[128 * 64];
  __shared__ int rowsS[128];
  __shared__ int winrow[128];
  __shared__ int nwin;

  if (t < 128) rowsS[t] = rows[(size_t)z * 4096 + tb + t];
  if (t == 0) nwin = 0;
  __syncthreads();

  const int lane = t & 63;
  const int wv = t >> 6;
  const int wr = (wv >> 1) * 64;
  const int wc = (wv & 1) * 64;
  const int fr = lane & 15;
  const int fg = lane >> 4;

  const unsigned short* Xbase = X + (size_t)z * 4096 * 512;
  const unsigned short* Wbase = W + (size_t)z * 1024 * 512;

  f32x4 acc[4][4] = {};

  for (int kt = 0; kt < 8; ++kt) {
    if (kt) __syncthreads();
    stage_tile(Xbase, 512, tb, kt * 64, Xs);
    stage_tile(Wbase, 512, tn, kt * 64, Ws);
    __syncthreads();
#pragma unroll
    for (int kk = 0; kk < 2; ++kk) {
      const int gb = kk * 64 + fg * 16;
      bf16x8 xf[4], wf[4];
#pragma unroll
      for (int i = 0; i < 4; ++i) {
        xf[i] = read_frag(Xs, wr + i * 16 + fr, gb);
        wf[i] = read_frag(Ws, wc + i * 16 + fr, gb);
      }
#pragma unroll
      for (int mi = 0; mi < 4; ++mi)
#pragma unroll
        for (int ni = 0; ni < 4; ++ni)
          acc[mi][ni] = __builtin_amdgcn_mfma_f32_16x16x32_bf16(xf[mi], wf[ni], acc[mi][ni], 0, 0, 0);
    }
  }

  // store active rows (cached: re-read by the fused reduce)
#pragma unroll
  for (int mi = 0; mi < 4; ++mi) {
#pragma unroll
    for (int j = 0; j < 4; ++j) {
      int rl = wr + mi * 16 + fg * 4 + j;
      if (tb + rl < cnt) {
        int b = rowsS[rl];
        size_t rowbase = (size_t)b * (16 * 1024) + (size_t)z * 1024;
#pragma unroll
        for (int ni = 0; ni < 4; ++ni) {
          int h = tn + wc + ni * 16 + fr;
          inner_out[rowbase + h] = acc[mi][ni][j];
        }
      }
    }
  }

  // ---- canonical last-writer-reduces (CUDA threadFenceReduction idiom) ----
  __threadfence();   // release this thread's inner stores (agent scope)
  __syncthreads();   // all threads' fences complete
  if (t < 128 && tb + t < cnt) {
    int b = rowsS[t];
    int old = atomicAdd(&done[b], 1);
    if (old == target[b] - 1) {
      int idx = atomicAdd(&nwin, 1);
      winrow[idx] = b;
    }
  }
  __syncthreads();
  int n = nwin;
  if (n > 0) {
    f32x4 bv = *((const f32x4*)bias + t);
    for (int wi = 0; wi < n; ++wi) {
      int b = winrow[wi];
      unsigned km = kmask[b];
      f32x4 s = bv;
      const f32x4* ip = (const f32x4*)(inner_out + (size_t)b * (16 * 1024)) + t;
#pragma unroll
      for (int k = 0; k < 16; ++k) {
        if ((km >> k) & 1) s += __builtin_nontemporal_load(ip + (size_t)k * 256);
      }
      __builtin_nontemporal_store(s, (f32x4*)out + (size_t)b * 256 + t);
    }
  }
}

extern "C" void kernel_launch(void* const* d_in, const int* in_sizes, int n_in,
                              void* d_out, int out_size, void* d_ws, size_t ws_size,
                              hipStream_t stream) {
  const float* x    = (const float*)d_in[0];
  const int*   mask = (const int*)d_in[1];
  const float* A    = (const float*)d_in[2];
  const float* B    = (const float*)d_in[3];
  const float* bias = (const float*)d_in[4];

  float* out   = (float*)d_out;
  float* inner = (float*)d_out + (size_t)4096 * 1024;

  // ws: x_bf 8MiB | A_t 16MiB | B_t 16MiB | pre 64MiB | rows 256KiB | counts | kmask/done/target
  if (ws_size < 109367296ull) return;
  char* ws = (char*)d_ws;
  unsigned short* x_bf = (unsigned short*)ws;
  unsigned short* A_t  = (unsigned short*)(ws + ((size_t)8 << 20));
  unsigned short* B_t  = (unsigned short*)(ws + ((size_t)24 << 20));
  unsigned short* pre  = (unsigned short*)(ws + ((size_t)40 << 20));
  char* base2          = ws + ((size_t)104 << 20);
  int* rows            = (int*)base2;                       // 256KiB
  int* counts          = (int*)(base2 + 262144);            // 64B
  unsigned* kmask      = (unsigned*)(base2 + 266240);       // 16KiB
  int* done            = (int*)(base2 + 266240 + 16384);    // 16KiB
  int* target          = (int*)(base2 + 266240 + 32768);    // 16KiB

  prep_kernel<<<6176, 256, 0, stream>>>(x, x_bf, A, A_t, B, B_t, mask, rows, counts,
                                        kmask, done, target, bias, out);

  gemm1_kernel<<<4096, 256, 0, stream>>>(x_bf, A_t, pre, inner, rows, counts);
  gemm2_kernel<<<dim3(8, 32, 16), 256, 0, stream>>>(pre, B_t, inner, rows, counts,
                                                    done, target, kmask, bias, out);
}

// Round 19
// 163.935 us; speedup vs baseline: 4.7348x; 4.7348x over previous
//
#include <hip/hip_runtime.h>

typedef __attribute__((ext_vector_type(8))) short bf16x8;
typedef __attribute__((ext_vector_type(4))) float f32x4;
typedef __attribute__((ext_vector_type(8))) unsigned short u16x8;

__device__ __forceinline__ unsigned short f2bf(float f) {
  union { float f; unsigned u; } v; v.f = f;
  unsigned r = v.u + 0x7fffu + ((v.u >> 16) & 1u);
  return (unsigned short)(r >> 16);
}

// ================= merged prep: cvt_x | transpose A | transpose B | compact =================
// grid: [0,2048) cvt_x | [2048,4096) trA | [4096,6144) trB | [6144,6160) compact
__global__ __launch_bounds__(256)
void prep_kernel(const float* __restrict__ x, unsigned short* __restrict__ x_bf,
                 const float* __restrict__ A, unsigned short* __restrict__ A_t,
                 const float* __restrict__ B, unsigned short* __restrict__ B_t,
                 const int* __restrict__ mask, int* __restrict__ rows,
                 int* __restrict__ counts) {
  __shared__ float tbuf[64][65];
  __shared__ int cnt, mcnt;
  const int bid = blockIdx.x;
  const int t = threadIdx.x;

  if (bid < 2048) {  // ---- cvt_x: f32 -> bf16, 32B read / 16B write per lane ----
    int slot = bid * 256 + t;
    f32x4 v0 = __builtin_nontemporal_load((const f32x4*)x + 2 * slot);
    f32x4 v1 = __builtin_nontemporal_load((const f32x4*)x + 2 * slot + 1);
    u16x8 o;
    o[0] = f2bf(v0[0]); o[1] = f2bf(v0[1]); o[2] = f2bf(v0[2]); o[3] = f2bf(v0[3]);
    o[4] = f2bf(v1[0]); o[5] = f2bf(v1[1]); o[6] = f2bf(v1[2]); o[7] = f2bf(v1[3]);
    ((u16x8*)x_bf)[slot] = o;
    return;
  }
  if (bid < 6144) {  // ---- transpose+convert, 64x64 tiles ----
    const float* in; unsigned short* out; int R, C, cx, ry, z;
    if (bid < 4096) {  // A: [16][1024][512] -> [16][512][1024]
      int idx = bid - 2048; z = idx >> 7; int local = idx & 127;
      R = 1024; C = 512; cx = local & 7; ry = local >> 3;
      in = A; out = A_t;
    } else {           // B: [16][512][1024] -> [16][1024][512]
      int idx = bid - 4096; z = idx >> 7; int local = idx & 127;
      R = 512; C = 1024; cx = local & 15; ry = local >> 4;
      in = B; out = B_t;
    }
    size_t eo = (size_t)z * R * C;
    const float* src = in + eo;
    unsigned short* dst = out + eo;
    int c0 = cx * 64, r0 = ry * 64;
    int tx = t & 63, ty = t >> 6;  // (64,4)
#pragma unroll
    for (int i = 0; i < 64; i += 4)
      tbuf[ty + i][tx] = __builtin_nontemporal_load(&src[(size_t)(r0 + ty + i) * C + (c0 + tx)]);
    __syncthreads();
#pragma unroll
    for (int i = 0; i < 64; i += 4)
      dst[(size_t)(c0 + ty + i) * R + (r0 + tx)] = f2bf(tbuf[tx][ty + i]);
    return;
  }
  // ---- compact (complement tail): rows[z][0..cnt)=active, [cnt..4096)=masked ----
  {
    int z = bid - 6144;
    if (t == 0) { cnt = 0; mcnt = 0; }
    __syncthreads();
    int* rz = rows + (size_t)z * 4096;
    for (int i = t; i < 4096; i += 256) {
      bool m = mask[(size_t)i * 16 + z] != 0;
      unsigned long long bal = __ballot(m);
      int lane = t & 63;
      int pa = __popcll(bal & ((1ull << lane) - 1ull));
      int ta = __popcll(bal);
      int base_a, base_m;
      if (lane == 0) { base_a = atomicAdd(&cnt, ta); base_m = atomicAdd(&mcnt, 64 - ta); }
      base_a = __shfl(base_a, 0);
      base_m = __shfl(base_m, 0);
      int pm = lane - pa;
      if (m) rz[base_a + pa] = i;
      else   rz[4095 - (base_m + pm)] = i;
    }
    __syncthreads();
    if (t == 0) counts[z] = cnt;
  }
}

// ================= GEMM building blocks (r11 structure) =================
__device__ __forceinline__ void stage_tile(const unsigned short* __restrict__ src,
                                           size_t row_stride, int row0, int k0,
                                           unsigned short* lds) {
  int t = threadIdx.x;
  int lane = t & 63;
  int w = t >> 6;
#pragma unroll
  for (int i = 0; i < 4; ++i) {
    int chunk = w * 4 + i;
    int row = chunk * 8 + (lane >> 3);
    int glog = (lane & 7) ^ (row & 7);
    const unsigned short* g = src + (size_t)(row0 + row) * row_stride + (size_t)(k0 + glog * 8);
    __builtin_amdgcn_global_load_lds((const __attribute__((address_space(1))) unsigned int*)g,
                                     (__attribute__((address_space(3))) unsigned int*)(lds + chunk * 512),
                                     16, 0, 0);
  }
}

__device__ __forceinline__ bf16x8 read_frag(const unsigned short* lds, int row, int gb) {
  int phys = (row * 128 + gb) ^ ((row & 7) << 4);
  return *(const bf16x8*)((const char*)lds + phys);
}

// ================= GEMM1 + fused masked-inner zero-fill =================
// 1D grid 4096: chunk = o&7 (XCD), pos = o>>3. pos<256: GEMM compute for experts {2k,2k+1}.
// pos>=256: nt zero-fill of the SAME experts' masked inner rows (write-only, no L2 pollution).
__global__ __launch_bounds__(256)
void gemm1_kernel(const unsigned short* __restrict__ X,
                  const unsigned short* __restrict__ W,
                  unsigned short* __restrict__ pre_out,
                  float* __restrict__ inner_out,
                  const int* __restrict__ rows,
                  const int* __restrict__ counts) {
  const int o = blockIdx.x;
  const int chunk = o & 7;
  const int pos = o >> 3;
  const int t = threadIdx.x;

  if (pos >= 256) {  // ---- zero-fill block: 32 masked row-slots of expert z ----
    int w = chunk * 256 + (pos - 256);   // 0..2047
    int z = w >> 7;                      // = chunk*2 + bit -> this chunk's experts
    int sub = w & 127;
    int cnt = counts[z];
    int slot0 = cnt + sub * 32;
    if (slot0 >= 4096) return;
    const int* rz = rows + (size_t)z * 4096;
    const f32x4 z4 = {0.f, 0.f, 0.f, 0.f};
#pragma unroll 4
    for (int i = 0; i < 32; ++i) {
      int slot = slot0 + i;
      if (slot >= 4096) break;
      int b = rz[slot];
      f32x4* p = (f32x4*)(inner_out + (size_t)b * (16 * 1024) + (size_t)z * 1024) + t;
      __builtin_nontemporal_store(z4, p);
    }
    return;
  }

  // ---- GEMM compute block ----
  int g = chunk * 256 + pos;           // 0..2047
  const int bx = g & 3;
  const int by = (g >> 2) & 31;
  const int z = g >> 7;
  const int cnt = counts[z];
  const int tb = by * 128;
  const int tn = bx * 128;
  if (tb >= cnt) return;  // masked rows need no pre

  __shared__ unsigned short Xs[128 * 64];
  __shared__ unsigned short Ws[128 * 64];
  __shared__ int rowsS[128];

  if (t < 128) rowsS[t] = rows[(size_t)z * 4096 + tb + t];
  __syncthreads();

  const int lane = t & 63;
  const int wv = t >> 6;
  const int wr = (wv >> 1) * 64;
  const int wc = (wv & 1) * 64;
  const int fr = lane & 15;
  const int fg = lane >> 4;

  const unsigned short* Wbase = W + (size_t)z * 512 * 1024;

  // hoist gather offsets: per-thread rows fixed across the K-loop
  int xoff[4];
#pragma unroll
  for (int i = 0; i < 4; ++i) {
    int chnk = wv * 4 + i;
    int row = chnk * 8 + (lane >> 3);
    int glog = (lane & 7) ^ (row & 7);
    xoff[i] = rowsS[row] * 1024 + glog * 8;
  }

  f32x4 acc[4][4] = {};

  for (int kt = 0; kt < 16; ++kt) {
    if (kt) __syncthreads();
    {
      const int k64 = kt * 64;
#pragma unroll
      for (int i = 0; i < 4; ++i) {
        int chnk = wv * 4 + i;
        __builtin_amdgcn_global_load_lds(
            (const __attribute__((address_space(1))) unsigned int*)(X + xoff[i] + k64),
            (__attribute__((address_space(3))) unsigned int*)(Xs + chnk * 512), 16, 0, 0);
      }
    }
    stage_tile(Wbase, 1024, tn, kt * 64, Ws);
    __syncthreads();
#pragma unroll
    for (int kk = 0; kk < 2; ++kk) {
      const int gb = kk * 64 + fg * 16;
      bf16x8 xf[4], wf[4];
#pragma unroll
      for (int i = 0; i < 4; ++i) {
        xf[i] = read_frag(Xs, wr + i * 16 + fr, gb);
        wf[i] = read_frag(Ws, wc + i * 16 + fr, gb);
      }
#pragma unroll
      for (int mi = 0; mi < 4; ++mi)
#pragma unroll
        for (int ni = 0; ni < 4; ++ni)
          acc[mi][ni] = __builtin_amdgcn_mfma_f32_16x16x32_bf16(xf[mi], wf[ni], acc[mi][ni], 0, 0, 0);
    }
  }

  // C/D layout: col = lane&15, row = (lane>>4)*4 + j
#pragma unroll
  for (int mi = 0; mi < 4; ++mi) {
#pragma unroll
    for (int j = 0; j < 4; ++j) {
      int rl = wr + mi * 16 + fg * 4 + j;
      size_t rowbase = (size_t)z * 4096 * 512 + (size_t)(tb + rl) * 512;
#pragma unroll
      for (int ni = 0; ni < 4; ++ni) {
        int m = tn + wc + ni * 16 + fr;
        pre_out[rowbase + m] = f2bf(acc[mi][ni][j]);  // re-read by GEMM2: keep cached
      }
    }
  }
}

// ================= GEMM2: inner = pre . B_t^T (K=512), T1 swizzle =================
// Masked rows are zero-filled by gemm1's dispatch -> tb>=cnt blocks return immediately,
// boundary blocks store only active rows.
__global__ __launch_bounds__(256)
void gemm2_kernel(const unsigned short* __restrict__ X,
                  const unsigned short* __restrict__ W,
                  float* __restrict__ inner_out,
                  const int* __restrict__ rows,
                  const int* __restrict__ counts) {
  const int gx = gridDim.x, gy = gridDim.y;
  int lin = blockIdx.x + gx * (blockIdx.y + gy * blockIdx.z);
  int cpx = (gx * gy * gridDim.z) >> 3;
  lin = (lin & 7) * cpx + (lin >> 3);
  int bx = lin % gx; lin /= gx;
  int by = lin % gy; lin /= gy;
  const int z = lin;
  const int cnt = counts[z];
  const int tb = by * 128;
  const int tn = bx * 128;
  const int t = threadIdx.x;

  if (tb >= cnt) return;  // masked rows already zero-filled in gemm1 dispatch

  __shared__ unsigned short Xs[128 * 64];
  __shared__ unsigned short Ws[128 * 64];
  __shared__ int rowsS[128];

  if (t < 128) rowsS[t] = rows[(size_t)z * 4096 + tb + t];
  __syncthreads();

  const int lane = t & 63;
  const int wv = t >> 6;
  const int wr = (wv >> 1) * 64;
  const int wc = (wv & 1) * 64;
  const int fr = lane & 15;
  const int fg = lane >> 4;

  const unsigned short* Xbase = X + (size_t)z * 4096 * 512;
  const unsigned short* Wbase = W + (size_t)z * 1024 * 512;

  f32x4 acc[4][4] = {};

  for (int kt = 0; kt < 8; ++kt) {
    if (kt) __syncthreads();
    stage_tile(Xbase, 512, tb, kt * 64, Xs);
    stage_tile(Wbase, 512, tn, kt * 64, Ws);
    __syncthreads();
#pragma unroll
    for (int kk = 0; kk < 2; ++kk) {
      const int gb = kk * 64 + fg * 16;
      bf16x8 xf[4], wf[4];
#pragma unroll
      for (int i = 0; i < 4; ++i) {
        xf[i] = read_frag(Xs, wr + i * 16 + fr, gb);
        wf[i] = read_frag(Ws, wc + i * 16 + fr, gb);
      }
#pragma unroll
      for (int mi = 0; mi < 4; ++mi)
#pragma unroll
        for (int ni = 0; ni < 4; ++ni)
          acc[mi][ni] = __builtin_amdgcn_mfma_f32_16x16x32_bf16(xf[mi], wf[ni], acc[mi][ni], 0, 0, 0);
    }
  }

#pragma unroll
  for (int mi = 0; mi < 4; ++mi) {
#pragma unroll
    for (int j = 0; j < 4; ++j) {
      int rl = wr + mi * 16 + fg * 4 + j;
      if (tb + rl < cnt) {
        int b = rowsS[rl];
        size_t rowbase = (size_t)b * (16 * 1024) + (size_t)z * 1024;
#pragma unroll
        for (int ni = 0; ni < 4; ++ni) {
          int h = tn + wc + ni * 16 + fr;
          inner_out[rowbase + h] = acc[mi][ni][j];  // re-read by reduce: keep cached (L3)
        }
      }
    }
  }
}

// ---- out[b] = bias + sum_{k: mask[b][k]} inner[b][k]; nt loads (inner dead after this) ----
__global__ __launch_bounds__(256)
void reduce_kernel(const float* __restrict__ inner, const float* __restrict__ bias,
                   const int* __restrict__ mask, float* __restrict__ out) {
  int b = blockIdx.x;
  int t = threadIdx.x;
  __shared__ int mrow[16];
  if (t < 16) mrow[t] = mask[(size_t)b * 16 + t];
  __syncthreads();
  f32x4 bv = *((const f32x4*)bias + t);
  f32x4 s = bv;
  const f32x4* ip = (const f32x4*)(inner + (size_t)b * (16 * 1024)) + t;
#pragma unroll
  for (int k = 0; k < 16; ++k) {
    if (mrow[k]) {
      f32x4 v = __builtin_nontemporal_load(ip + (size_t)k * 256);
      s += v;
    }
  }
  __builtin_nontemporal_store(s, (f32x4*)out + (size_t)b * 256 + t);
}

extern "C" void kernel_launch(void* const* d_in, const int* in_sizes, int n_in,
                              void* d_out, int out_size, void* d_ws, size_t ws_size,
                              hipStream_t stream) {
  const float* x    = (const float*)d_in[0];
  const int*   mask = (const int*)d_in[1];
  const float* A    = (const float*)d_in[2];
  const float* B    = (const float*)d_in[3];
  const float* bias = (const float*)d_in[4];

  float* out   = (float*)d_out;
  float* inner = (float*)d_out + (size_t)4096 * 1024;

  // ws layout: x_bf 8MiB | A_t 16MiB | B_t 16MiB | pre 64MiB | rows 256KiB | counts
  if (ws_size < 109314112ull) return;
  char* ws = (char*)d_ws;
  unsigned short* x_bf = (unsigned short*)ws;
  unsigned short* A_t  = (unsigned short*)(ws + ((size_t)8 << 20));
  unsigned short* B_t  = (unsigned short*)(ws + ((size_t)24 << 20));
  unsigned short* pre  = (unsigned short*)(ws + ((size_t)40 << 20));
  int* rows            = (int*)(ws + ((size_t)104 << 20));
  int* counts          = (int*)(ws + ((size_t)104 << 20) + 262144);

  prep_kernel<<<6160, 256, 0, stream>>>(x, x_bf, A, A_t, B, B_t, mask, rows, counts);

  gemm1_kernel<<<4096, 256, 0, stream>>>(x_bf, A_t, pre, inner, rows, counts);
  gemm2_kernel<<<dim3(8, 32, 16), 256, 0, stream>>>(pre, B_t, inner, rows, counts);

  reduce_kernel<<<4096, 256, 0, stream>>>(inner, bias, mask, out);
}